// Round 11
// baseline (892.060 us; speedup 1.0000x reference)
//
#include <hip/hip_runtime.h>
#include <hip/hip_bf16.h>

#define N 4096
#define D 64
#define NH 4
#define NSTEP 4
#define HSTRIDE 262144   // elements per head in fragment-major arrays (4096*64)

typedef short bf16x8 __attribute__((ext_vector_type(8)));
typedef float f32x4 __attribute__((ext_vector_type(4)));
typedef __hip_bfloat16 bf16;
typedef unsigned long long u64;

// ws layout (bytes)
static const size_t OFF_MASK = 0;                              // NSTEP*N*64 u64 = 8 MB
static const size_t OFF_RMAX = (size_t)8 << 20;                // NH*N f32 = 64 KB
static const size_t OFF_HNHI = (size_t)9 << 20;                // NH*HSTRIDE bf16 = 2 MB
static const size_t OFF_HNLO = (size_t)11 << 20;               // 2 MB
static const size_t OFF_HTHI = (size_t)13 << 20;               // 2 MB
static const size_t OFF_HTLO = (size_t)15 << 20;               // 2 MB
static const size_t OFF_HOUT = (size_t)17 << 20;               // NH*N*D f32 = 4 MB
static const size_t OFF_CM   = (size_t)21 << 20;               // NH*D f32

// Coalesced mask pack (R8 version). mt[row][ln][w] (u64),
// bit i = adj[row][w*1024 + i*16 + ln].
__global__ void k_packadj(const int* __restrict__ adj, u64* __restrict__ mt) {
    int t = threadIdx.x;
    int lane = t & 63;
    int row = blockIdx.x * 16 + (t >> 6) * 4 + (lane >> 4);   // 16 rows per block
    int sub = lane & 15;
    int w = sub & 3;
    int c4 = sub >> 2;
    const int* rowp = adj + (size_t)row * N + w * 1024 + c4 * 4;
    u64 m0 = 0, m1 = 0, m2 = 0, m3 = 0;
    for (int i = 0; i < 64; ++i) {
        int4 v = *(const int4*)(rowp + i * 16);
        u64 b = 1ull << i;
        if (v.x > 0) m0 |= b;
        if (v.y > 0) m1 |= b;
        if (v.z > 0) m2 |= b;
        if (v.w > 0) m3 |= b;
    }
    u64* out = mt + (size_t)row * 64;
    out[(c4 * 4 + 0) * 4 + w] = m0;
    out[(c4 * 4 + 1) * 4 + w] = m1;
    out[(c4 * 4 + 2) * 4 + w] = m2;
    out[(c4 * 4 + 3) * 4 + w] = m3;
}

// h = X @ W[head] in fp32; fragment-major hi/lo outputs written coalesced via LDS.
// When use_hout != 0, input features = 4-head mean of hout (== old k_combine).
__global__ void k_phase0(const float* __restrict__ X, const float* __restrict__ hprev,
                         int use_hout, const float* __restrict__ W,
                         bf16* __restrict__ hnf_hi, bf16* __restrict__ hnf_lo,
                         bf16* __restrict__ htf_hi, bf16* __restrict__ htf_lo,
                         float* __restrict__ colmean) {
    __shared__ float Xs[64][65];
    __shared__ float Wsh[64][64];
    __shared__ float hbuf[64][68];
    __shared__ float rnbuf[64];
    __shared__ float colsum[64];
    int head = blockIdx.y;
    int r0 = blockIdx.x * 64;
    int t = threadIdx.x;
    for (int i = 0; i < 16; ++i) {
        int idx = t + 256 * i;
        int r = idx >> 6, c = idx & 63;
        float xv;
        if (use_hout) {
            size_t o = (size_t)(r0 + r) * 64 + c;
            xv = 0.25f * (hprev[o] + hprev[o + N * 64] + hprev[o + 2 * N * 64] + hprev[o + 3 * N * 64]);
        } else {
            xv = X[(size_t)(r0 + r) * 64 + c];
        }
        Xs[r][c] = xv;
        Wsh[r][c] = W[(size_t)head * 4096 + idx];
    }
    if (t < 64) colsum[t] = 0.f;
    __syncthreads();
    int lane = t & 63, w = t >> 6;
    int lr = w * 16 + (lane >> 2);
    int e0 = (lane & 3) * 16;
    float acc[16];
#pragma unroll
    for (int j = 0; j < 16; ++j) acc[j] = 0.f;
    for (int d = 0; d < 64; ++d) {
        float xv = Xs[lr][d];
#pragma unroll
        for (int j = 0; j < 16; ++j) acc[j] = fmaf(xv, Wsh[d][e0 + j], acc[j]);
    }
    float ss = 0.f;
#pragma unroll
    for (int j = 0; j < 16; ++j) ss = fmaf(acc[j], acc[j], ss);
    ss += __shfl_xor(ss, 1, 64);
    ss += __shfl_xor(ss, 2, 64);
    float rn = 1.0f / (sqrtf(ss) + 1e-12f);
#pragma unroll
    for (int j = 0; j < 16; ++j) hbuf[lr][e0 + j] = acc[j];
    if ((lane & 3) == 0) rnbuf[lr] = rn;
#pragma unroll
    for (int j = 0; j < 16; ++j) {
        float v = acc[j];
        v += __shfl_xor(v, 4, 64);
        v += __shfl_xor(v, 8, 64);
        v += __shfl_xor(v, 16, 64);
        v += __shfl_xor(v, 32, 64);
        if ((lane >> 2) == 0) atomicAdd(&colsum[e0 + j], v);
    }
    __syncthreads();
    if (t < 64) atomicAdd(&colmean[head * 64 + t], colsum[t] * (1.0f / N));

    size_t hb = (size_t)head * HSTRIDE;
    size_t hnbase = hb + (size_t)r0 * 64;
    size_t htbase = hb + (size_t)blockIdx.x * 4096;
#pragma unroll
    for (int u = 0; u < 2; ++u) {
        int idx16 = t * 2 + u;
        {
            int lnn = idx16 & 15, q = (idx16 >> 4) & 3, half = (idx16 >> 6) & 1, ctl = idx16 >> 7;
            int row = ctl * 16 + lnn, d0 = half * 32 + q * 8;
            float rr = rnbuf[row];
            bf16x8 hi8, lo8;
#pragma unroll
            for (int j = 0; j < 8; ++j) {
                float hnv = hbuf[row][d0 + j] * rr;
                bf16 nhi = __float2bfloat16(hnv);
                bf16 nlo = __float2bfloat16(hnv - __bfloat162float(nhi));
                hi8[j] = *(short*)&nhi;
                lo8[j] = *(short*)&nlo;
            }
            *(bf16x8*)(hnf_hi + hnbase + (size_t)idx16 * 8) = hi8;
            *(bf16x8*)(hnf_lo + hnbase + (size_t)idx16 * 8) = lo8;
        }
        {
            int dln = idx16 & 15, qq = (idx16 >> 4) & 3, half = (idx16 >> 6) & 1, nt = idx16 >> 7;
            int d = nt * 16 + dln, cbase = half * 32 + qq * 8;
            bf16x8 hi8, lo8;
#pragma unroll
            for (int j = 0; j < 8; ++j) {
                float hv = hbuf[cbase + j][d];
                bf16 hhi = __float2bfloat16(hv);
                bf16 hlo = __float2bfloat16(hv - __bfloat162float(hhi));
                hi8[j] = *(short*)&hhi;
                lo8[j] = *(short*)&hlo;
            }
            *(bf16x8*)(htf_hi + htbase + (size_t)idx16 * 8) = hi8;
            *(bf16x8*)(htf_lo + htbase + (size_t)idx16 * 8) = lo8;
        }
    }
}

struct BFrag { bf16x8 h0, h1, l0, l1; };

__device__ __forceinline__ BFrag load_bfrag(const bf16* __restrict__ hfh,
                                            const bf16* __restrict__ hfl,
                                            int ct, int lane) {
    BFrag f;
    size_t base = (size_t)ct * 1024 + lane * 8;
    f.h0 = *(const bf16x8*)(hfh + base);
    f.h1 = *(const bf16x8*)(hfh + base + 512);
    f.l0 = *(const bf16x8*)(hfl + base);
    f.l1 = *(const bf16x8*)(hfl + base + 512);
    return f;
}

// split-bf16 sim: identical sequence in both kernels -> bit-identical keep rule.
__device__ __forceinline__ f32x4 sim_mfma(const BFrag& b,
                                          bf16x8 a0h, bf16x8 a1h, bf16x8 a0l, bf16x8 a1l) {
    f32x4 s = {0.f, 0.f, 0.f, 0.f};
    s = __builtin_amdgcn_mfma_f32_16x16x32_bf16(a0h, b.h0, s, 0, 0, 0);
    s = __builtin_amdgcn_mfma_f32_16x16x32_bf16(a1h, b.h1, s, 0, 0, 0);
    s = __builtin_amdgcn_mfma_f32_16x16x32_bf16(a0l, b.h0, s, 0, 0, 0);
    s = __builtin_amdgcn_mfma_f32_16x16x32_bf16(a1l, b.h1, s, 0, 0, 0);
    s = __builtin_amdgcn_mfma_f32_16x16x32_bf16(a0h, b.l0, s, 0, 0, 0);
    s = __builtin_amdgcn_mfma_f32_16x16x32_bf16(a1h, b.l1, s, 0, 0, 0);
    return s;
}

// PASS A as its own kernel: small register state -> 4 waves/SIMD.
// Block = 32 rows (2 row-tiles), 4 waves x 1024 columns; writes full row-max.
__launch_bounds__(256, 4)
__global__ void k_attn_a(const bf16* __restrict__ hnf_hi, const bf16* __restrict__ hnf_lo,
                         const u64* __restrict__ mt, float* __restrict__ rowmax) {
    __shared__ float maxb[4][32];
    int bid = blockIdx.x;
    int head = (bid & 7) >> 1;
    int rw = (((bid >> 3) << 1) | (bid & 1)) * 32;
    int t = threadIdx.x;
    int w = t >> 6, lane = t & 63;
    int ln = lane & 15, quad = lane >> 4;
    const bf16* hfh = hnf_hi + (size_t)head * HSTRIDE;
    const bf16* hfl = hnf_lo + (size_t)head * HSTRIDE;
    bf16x8 ah0[2], ah1[2], al0[2], al1[2];
#pragma unroll
    for (int rt = 0; rt < 2; ++rt) {
        size_t base = (size_t)((rw >> 4) + rt) * 1024 + lane * 8;
        ah0[rt] = *(const bf16x8*)(hfh + base);
        ah1[rt] = *(const bf16x8*)(hfh + base + 512);
        al0[rt] = *(const bf16x8*)(hfl + base);
        al1[rt] = *(const bf16x8*)(hfl + base + 512);
    }
    u64 mreg[2][4];
#pragma unroll
    for (int rt = 0; rt < 2; ++rt)
#pragma unroll
        for (int r = 0; r < 4; ++r)
            mreg[rt][r] = mt[((size_t)(rw + rt * 16 + quad * 4 + r) * 16 + ln) * 4 + w];

    const float NEGINF = -__builtin_inff();
    float m4[2][4];
#pragma unroll
    for (int rt = 0; rt < 2; ++rt)
#pragma unroll
        for (int r = 0; r < 4; ++r) m4[rt][r] = NEGINF;
    int ct0 = w * 64;

    for (int bi = 0; bi < 64; ++bi) {
        BFrag bt = load_bfrag(hfh, hfl, ct0 + bi, lane);
#pragma unroll
        for (int rt = 0; rt < 2; ++rt) {
            f32x4 s = sim_mfma(bt, ah0[rt], ah1[rt], al0[rt], al1[rt]);
#pragma unroll
            for (int r = 0; r < 4; ++r) {
                unsigned int bit = (unsigned int)(mreg[rt][r] >> bi) & 1u;
                float v = bit ? s[r] : NEGINF;
                m4[rt][r] = fmaxf(m4[rt][r], v);
            }
        }
    }
#pragma unroll
    for (int rt = 0; rt < 2; ++rt)
#pragma unroll
        for (int r = 0; r < 4; ++r) {
            float v = m4[rt][r];
            v = fmaxf(v, __shfl_xor(v, 1, 64));
            v = fmaxf(v, __shfl_xor(v, 2, 64));
            v = fmaxf(v, __shfl_xor(v, 4, 64));
            v = fmaxf(v, __shfl_xor(v, 8, 64));
            if (ln == 0) maxb[w][rt * 16 + quad * 4 + r] = v;
        }
    __syncthreads();
    if (t < 32)
        rowmax[(size_t)head * N + rw + t] =
            fmaxf(fmaxf(maxb[0][t], maxb[1][t]), fmaxf(maxb[2][t], maxb[3][t]));
}

// PASS B: keep rule, exp, P, PV. Natural registers (no forcing -> no spill).
__launch_bounds__(256, 2)
__global__ void k_attn_b(const bf16* __restrict__ hnf_hi, const bf16* __restrict__ hnf_lo,
                         const bf16* __restrict__ htf_hi, const bf16* __restrict__ htf_lo,
                         const u64* __restrict__ mt, const float* __restrict__ rowmax,
                         const float* __restrict__ colmean, float* __restrict__ hout) {
    __shared__ bf16 Plds[4][2][16 * 36];
    __shared__ float lbuf[4][16];
    __shared__ float pvbuf[4][16][66];
    int bid = blockIdx.x;
    int head = (bid & 7) >> 1;
    int rw = (((bid >> 3) << 1) | (bid & 1)) * 32;
    int t = threadIdx.x;
    int w = t >> 6, lane = t & 63;
    int ln = lane & 15, quad = lane >> 4;
    const bf16* hfh = hnf_hi + (size_t)head * HSTRIDE;
    const bf16* hfl = hnf_lo + (size_t)head * HSTRIDE;
    bf16x8 ah0[2], ah1[2], al0[2], al1[2];
#pragma unroll
    for (int rt = 0; rt < 2; ++rt) {
        size_t base = (size_t)((rw >> 4) + rt) * 1024 + lane * 8;
        ah0[rt] = *(const bf16x8*)(hfh + base);
        ah1[rt] = *(const bf16x8*)(hfh + base + 512);
        al0[rt] = *(const bf16x8*)(hfl + base);
        al1[rt] = *(const bf16x8*)(hfl + base + 512);
    }
    u64 mreg[2][4];
    float m4[2][4];
#pragma unroll
    for (int rt = 0; rt < 2; ++rt)
#pragma unroll
        for (int r = 0; r < 4; ++r) {
            int row = rw + rt * 16 + quad * 4 + r;
            mreg[rt][r] = mt[((size_t)row * 16 + ln) * 4 + w];
            m4[rt][r] = rowmax[(size_t)head * N + row];
        }

    const float NEGINF = -__builtin_inff();
    int ct0 = w * 64;
    const bf16* tfh = htf_hi + (size_t)head * HSTRIDE;
    const bf16* tfl = htf_lo + (size_t)head * HSTRIDE;
    float l4[2][4];
    f32x4 pv[2][4];
#pragma unroll
    for (int rt = 0; rt < 2; ++rt)
#pragma unroll
        for (int r = 0; r < 4; ++r) {
            l4[rt][r] = 0.f;
            pv[rt][r] = (f32x4){0.f, 0.f, 0.f, 0.f};
        }
    bf16* P0 = &Plds[w][0][0];
    bf16* P1 = &Plds[w][1][0];
    for (int fi = 0; fi < 32; ++fi) {
        BFrag bt[2];
#pragma unroll
        for (int tt = 0; tt < 2; ++tt) bt[tt] = load_bfrag(hfh, hfl, ct0 + fi * 2 + tt, lane);
#pragma unroll
        for (int tt = 0; tt < 2; ++tt) {
            int bi = fi * 2 + tt;
#pragma unroll
            for (int rt = 0; rt < 2; ++rt) {
                f32x4 s = sim_mfma(bt[tt], ah0[rt], ah1[rt], al0[rt], al1[rt]);
                bf16* P = rt ? P1 : P0;
#pragma unroll
                for (int r = 0; r < 4; ++r) {
                    unsigned int bit = (unsigned int)(mreg[rt][r] >> bi) & 1u;
                    bool keep = bit && (s[r] >= 0.5f * m4[rt][r]);
                    float arg = keep ? 5.0f * (s[r] - m4[rt][r]) : NEGINF;
                    float p = __expf(arg);
                    bf16 pb = __float2bfloat16(p);
                    l4[rt][r] += __bfloat162float(pb);   // denominator from the ROUNDED p
                    P[(quad * 4 + r) * 36 + tt * 16 + ln] = pb;
                }
            }
        }
        __builtin_amdgcn_wave_barrier();
        bf16x8 pa0 = *(const bf16x8*)(P0 + ln * 36 + quad * 8);
        bf16x8 pa1 = *(const bf16x8*)(P1 + ln * 36 + quad * 8);
        int c0 = w * 1024 + fi * 32;
        int g = c0 >> 6, half = (c0 >> 5) & 1;
#pragma unroll
        for (int nt = 0; nt < 4; ++nt) {
            size_t base = (size_t)(g * 8 + nt * 2 + half) * 512 + lane * 8;
            bf16x8 bh = *(const bf16x8*)(tfh + base);
            bf16x8 bl = *(const bf16x8*)(tfl + base);
            pv[0][nt] = __builtin_amdgcn_mfma_f32_16x16x32_bf16(pa0, bh, pv[0][nt], 0, 0, 0);
            pv[0][nt] = __builtin_amdgcn_mfma_f32_16x16x32_bf16(pa0, bl, pv[0][nt], 0, 0, 0);
            pv[1][nt] = __builtin_amdgcn_mfma_f32_16x16x32_bf16(pa1, bh, pv[1][nt], 0, 0, 0);
            pv[1][nt] = __builtin_amdgcn_mfma_f32_16x16x32_bf16(pa1, bl, pv[1][nt], 0, 0, 0);
        }
        __builtin_amdgcn_wave_barrier();
    }

    for (int rt = 0; rt < 2; ++rt) {
#pragma unroll
        for (int r = 0; r < 4; ++r) {
            float v = l4[rt][r];
            v += __shfl_xor(v, 1, 64);
            v += __shfl_xor(v, 2, 64);
            v += __shfl_xor(v, 4, 64);
            v += __shfl_xor(v, 8, 64);
            if (ln == 0) lbuf[w][quad * 4 + r] = v;
        }
#pragma unroll
        for (int nt = 0; nt < 4; ++nt)
#pragma unroll
            for (int r = 0; r < 4; ++r)
                pvbuf[w][quad * 4 + r][nt * 16 + ln] = pv[rt][nt][r];
        __syncthreads();
        {
            int row = t >> 4;
            int c4 = (t & 15) * 4;
            float lsum = lbuf[0][row] + lbuf[1][row] + lbuf[2][row] + lbuf[3][row];
            float inv = (lsum > 0.f) ? 1.0f / lsum : 0.f;
            float4 o;
            float* op = &o.x;
#pragma unroll
            for (int i = 0; i < 4; ++i) {
                int col = c4 + i;
                float v = pvbuf[0][row][col] + pvbuf[1][row][col]
                        + pvbuf[2][row][col] + pvbuf[3][row][col];
                v = (lsum > 0.f) ? v * inv : colmean[head * 64 + col];
                op[i] = (v > 0.f) ? v : (__expf(v) - 1.0f);
            }
            *(float4*)(hout + ((size_t)head * N + rw + rt * 16 + row) * 64 + c4) = o;
        }
        __syncthreads();
    }
}

__global__ void k_combine(const float* __restrict__ hout, float* __restrict__ outp) {
    int i = blockIdx.x * 256 + threadIdx.x;
    float v = 0.25f * (hout[i] + hout[i + N * 64] + hout[i + 2 * N * 64] + hout[i + 3 * N * 64]);
    outp[i] = v;
}

extern "C" void kernel_launch(void* const* d_in, const int* in_sizes, int n_in,
                              void* d_out, int out_size, void* d_ws, size_t ws_size,
                              hipStream_t stream) {
    const float* features_in = (const float*)d_in[0];
    const int* adj = (const int*)d_in[1];
    const float* Ws = (const float*)d_in[2];
    char* ws = (char*)d_ws;
    u64* mt = (u64*)(ws + OFF_MASK);
    float* rowmax = (float*)(ws + OFF_RMAX);
    bf16* hnf_hi = (bf16*)(ws + OFF_HNHI);
    bf16* hnf_lo = (bf16*)(ws + OFF_HNLO);
    bf16* htf_hi = (bf16*)(ws + OFF_HTHI);
    bf16* htf_lo = (bf16*)(ws + OFF_HTLO);
    float* hout = (float*)(ws + OFF_HOUT);
    float* cm = (float*)(ws + OFF_CM);

    k_packadj<<<dim3(NSTEP * N / 16), dim3(256), 0, stream>>>(adj, mt);
    for (int s = 0; s < NSTEP; ++s) {
        hipMemsetAsync(cm, 0, NH * D * sizeof(float), stream);
        k_phase0<<<dim3(64, NH), dim3(256), 0, stream>>>(features_in, hout, (s != 0),
                                                         Ws + (size_t)s * NH * D * D,
                                                         hnf_hi, hnf_lo, htf_hi, htf_lo, cm);
        k_attn_a<<<dim3(N / 32 * NH), dim3(256), 0, stream>>>(hnf_hi, hnf_lo,
                                                              mt + (size_t)s * N * 64, rowmax);
        k_attn_b<<<dim3(N / 32 * NH), dim3(256), 0, stream>>>(hnf_hi, hnf_lo, htf_hi, htf_lo,
                                                              mt + (size_t)s * N * 64, rowmax,
                                                              cm, hout);
    }
    k_combine<<<dim3(N * D / 256), dim3(256), 0, stream>>>(hout, (float*)d_out);
}

// Round 12
// 791.845 us; speedup vs baseline: 1.1266x; 1.1266x over previous
//
#include <hip/hip_runtime.h>
#include <hip/hip_bf16.h>

#define N 4096
#define D 64
#define NH 4
#define NSTEP 4
#define HSTRIDE 262144   // elements per head in fragment-major arrays (4096*64)

typedef short bf16x8 __attribute__((ext_vector_type(8)));
typedef float f32x4 __attribute__((ext_vector_type(4)));
typedef __hip_bfloat16 bf16;
typedef unsigned long long u64;

// ws layout (bytes)
static const size_t OFF_MASK = 0;                              // NSTEP*N*64 u64 = 8 MB
static const size_t OFF_FEAT = (size_t)8 << 20;                // N*D f32 = 1 MB
static const size_t OFF_HNHI = (size_t)9 << 20;                // NH*HSTRIDE bf16 = 2 MB
static const size_t OFF_HNLO = (size_t)11 << 20;               // 2 MB
static const size_t OFF_HTHI = (size_t)13 << 20;               // 2 MB
static const size_t OFF_HTLO = (size_t)15 << 20;               // 2 MB
static const size_t OFF_HOUT = (size_t)17 << 20;               // NH*N*D f32 = 4 MB
static const size_t OFF_CM   = (size_t)21 << 20;               // NH*D f32

// Coalesced mask pack (R8 version). mt[row][ln][w] (u64),
// bit i = adj[row][w*1024 + i*16 + ln].
__global__ void k_packadj(const int* __restrict__ adj, u64* __restrict__ mt) {
    int t = threadIdx.x;
    int lane = t & 63;
    int row = blockIdx.x * 16 + (t >> 6) * 4 + (lane >> 4);   // 16 rows per block
    int sub = lane & 15;
    int w = sub & 3;
    int c4 = sub >> 2;
    const int* rowp = adj + (size_t)row * N + w * 1024 + c4 * 4;
    u64 m0 = 0, m1 = 0, m2 = 0, m3 = 0;
    for (int i = 0; i < 64; ++i) {
        int4 v = *(const int4*)(rowp + i * 16);
        u64 b = 1ull << i;
        if (v.x > 0) m0 |= b;
        if (v.y > 0) m1 |= b;
        if (v.z > 0) m2 |= b;
        if (v.w > 0) m3 |= b;
    }
    u64* out = mt + (size_t)row * 64;
    out[(c4 * 4 + 0) * 4 + w] = m0;
    out[(c4 * 4 + 1) * 4 + w] = m1;
    out[(c4 * 4 + 2) * 4 + w] = m2;
    out[(c4 * 4 + 3) * 4 + w] = m3;
}

// h = X @ W[head] in fp32; fragment-major hi/lo outputs written coalesced via LDS.
// 1D grid with the SAME head->XCD pinning as k_attn, so each head's hn/ht lands in
// the L2s of the XCD pair that will consume it.
__global__ void k_phase0(const float* __restrict__ X, const float* __restrict__ W,
                         bf16* __restrict__ hnf_hi, bf16* __restrict__ hnf_lo,
                         bf16* __restrict__ htf_hi, bf16* __restrict__ htf_lo,
                         float* __restrict__ colmean) {
    __shared__ float Xs[64][65];
    __shared__ float Wsh[64][64];
    __shared__ float hbuf[64][68];
    __shared__ float rnbuf[64];
    __shared__ float colsum[64];
    int bid = blockIdx.x;
    int head = (bid & 7) >> 1;
    int rb = ((bid >> 3) << 1) | (bid & 1);
    int r0 = rb * 64;
    int t = threadIdx.x;
    for (int i = 0; i < 16; ++i) {
        int idx = t + 256 * i;
        int r = idx >> 6, c = idx & 63;
        Xs[r][c] = X[(size_t)(r0 + r) * 64 + c];
        Wsh[r][c] = W[(size_t)head * 4096 + idx];
    }
    if (t < 64) colsum[t] = 0.f;
    __syncthreads();
    int lane = t & 63, w = t >> 6;
    int lr = w * 16 + (lane >> 2);
    int e0 = (lane & 3) * 16;
    float acc[16];
#pragma unroll
    for (int j = 0; j < 16; ++j) acc[j] = 0.f;
    for (int d = 0; d < 64; ++d) {
        float xv = Xs[lr][d];
#pragma unroll
        for (int j = 0; j < 16; ++j) acc[j] = fmaf(xv, Wsh[d][e0 + j], acc[j]);
    }
    float ss = 0.f;
#pragma unroll
    for (int j = 0; j < 16; ++j) ss = fmaf(acc[j], acc[j], ss);
    ss += __shfl_xor(ss, 1, 64);
    ss += __shfl_xor(ss, 2, 64);
    float rn = 1.0f / (sqrtf(ss) + 1e-12f);
#pragma unroll
    for (int j = 0; j < 16; ++j) hbuf[lr][e0 + j] = acc[j];
    if ((lane & 3) == 0) rnbuf[lr] = rn;
#pragma unroll
    for (int j = 0; j < 16; ++j) {
        float v = acc[j];
        v += __shfl_xor(v, 4, 64);
        v += __shfl_xor(v, 8, 64);
        v += __shfl_xor(v, 16, 64);
        v += __shfl_xor(v, 32, 64);
        if ((lane >> 2) == 0) atomicAdd(&colsum[e0 + j], v);
    }
    __syncthreads();
    if (t < 64) atomicAdd(&colmean[head * 64 + t], colsum[t] * (1.0f / N));

    // writer phase: contiguous bf16x8 stores, values bit-identical to direct scatter
    size_t hb = (size_t)head * HSTRIDE;
    size_t hnbase = hb + (size_t)r0 * 64;          // ct0*1024
    size_t htbase = hb + (size_t)rb * 4096;        // g*4096
#pragma unroll
    for (int u = 0; u < 2; ++u) {
        int idx16 = t * 2 + u;
        // hn fragment: row = ctl*16+lnn, d0 = half*32+q*8
        {
            int lnn = idx16 & 15, q = (idx16 >> 4) & 3, half = (idx16 >> 6) & 1, ctl = idx16 >> 7;
            int row = ctl * 16 + lnn, d0 = half * 32 + q * 8;
            float rr = rnbuf[row];
            bf16x8 hi8, lo8;
#pragma unroll
            for (int j = 0; j < 8; ++j) {
                float hnv = hbuf[row][d0 + j] * rr;
                bf16 nhi = __float2bfloat16(hnv);
                bf16 nlo = __float2bfloat16(hnv - __bfloat162float(nhi));
                hi8[j] = *(short*)&nhi;
                lo8[j] = *(short*)&nlo;
            }
            *(bf16x8*)(hnf_hi + hnbase + (size_t)idx16 * 8) = hi8;
            *(bf16x8*)(hnf_lo + hnbase + (size_t)idx16 * 8) = lo8;
        }
        // ht fragment: d = nt*16+dln, rows cbase..cbase+7
        {
            int dln = idx16 & 15, qq = (idx16 >> 4) & 3, half = (idx16 >> 6) & 1, nt = idx16 >> 7;
            int d = nt * 16 + dln, cbase = half * 32 + qq * 8;
            bf16x8 hi8, lo8;
#pragma unroll
            for (int j = 0; j < 8; ++j) {
                float hv = hbuf[cbase + j][d];
                bf16 hhi = __float2bfloat16(hv);
                bf16 hlo = __float2bfloat16(hv - __bfloat162float(hhi));
                hi8[j] = *(short*)&hhi;
                lo8[j] = *(short*)&hlo;
            }
            *(bf16x8*)(htf_hi + htbase + (size_t)idx16 * 8) = hi8;
            *(bf16x8*)(htf_lo + htbase + (size_t)idx16 * 8) = lo8;
        }
    }
}

struct BFrag { bf16x8 h0, h1, l0, l1; };

__device__ __forceinline__ BFrag load_bfrag(const bf16* __restrict__ hfh,
                                            const bf16* __restrict__ hfl,
                                            int ct, int lane) {
    BFrag f;
    size_t base = (size_t)ct * 1024 + lane * 8;
    f.h0 = *(const bf16x8*)(hfh + base);
    f.h1 = *(const bf16x8*)(hfh + base + 512);
    f.l0 = *(const bf16x8*)(hfl + base);
    f.l1 = *(const bf16x8*)(hfl + base + 512);
    return f;
}

// split-bf16 sim: identical sequence in both passes -> bit-identical keep rule.
__device__ __forceinline__ f32x4 sim_mfma(const BFrag& b,
                                          bf16x8 a0h, bf16x8 a1h, bf16x8 a0l, bf16x8 a1l) {
    f32x4 s = {0.f, 0.f, 0.f, 0.f};
    s = __builtin_amdgcn_mfma_f32_16x16x32_bf16(a0h, b.h0, s, 0, 0, 0);
    s = __builtin_amdgcn_mfma_f32_16x16x32_bf16(a1h, b.h1, s, 0, 0, 0);
    s = __builtin_amdgcn_mfma_f32_16x16x32_bf16(a0l, b.h0, s, 0, 0, 0);
    s = __builtin_amdgcn_mfma_f32_16x16x32_bf16(a1l, b.h1, s, 0, 0, 0);
    s = __builtin_amdgcn_mfma_f32_16x16x32_bf16(a0h, b.l0, s, 0, 0, 0);
    s = __builtin_amdgcn_mfma_f32_16x16x32_bf16(a1h, b.l1, s, 0, 0, 0);
    return s;
}

// fused two-pass masked attention (R8 structure, verbatim). Block = 32 rows (two
// 16-row tiles sharing every B-fragment load), 256 threads: 4 waves x 1024 columns.
__launch_bounds__(256, 2)
__global__ void k_attn(const bf16* __restrict__ hnf_hi, const bf16* __restrict__ hnf_lo,
                       const bf16* __restrict__ htf_hi, const bf16* __restrict__ htf_lo,
                       const u64* __restrict__ mt,
                       const float* __restrict__ colmean,
                       float* __restrict__ hout) {
    __shared__ bf16 Plds[4][2][16 * 36];   // per-wave P tiles (rt x 16 rows x 32 cols)
    __shared__ float maxb[4][32];
    __shared__ float lbuf[4][16];
    __shared__ float pvbuf[4][16][66];
    int bid = blockIdx.x;
    int head = (bid & 7) >> 1;
    int rw = (((bid >> 3) << 1) | (bid & 1)) * 32;
    int t = threadIdx.x;
    int w = t >> 6, lane = t & 63;
    int ln = lane & 15, quad = lane >> 4;
    const bf16* hfh = hnf_hi + (size_t)head * HSTRIDE;
    const bf16* hfl = hnf_lo + (size_t)head * HSTRIDE;
    bf16x8 ah0[2], ah1[2], al0[2], al1[2];
#pragma unroll
    for (int rt = 0; rt < 2; ++rt) {
        size_t base = (size_t)((rw >> 4) + rt) * 1024 + lane * 8;
        ah0[rt] = *(const bf16x8*)(hfh + base);
        ah1[rt] = *(const bf16x8*)(hfh + base + 512);
        al0[rt] = *(const bf16x8*)(hfl + base);
        al1[rt] = *(const bf16x8*)(hfl + base + 512);
    }
    u64 mreg[2][4];
#pragma unroll
    for (int rt = 0; rt < 2; ++rt)
#pragma unroll
        for (int r = 0; r < 4; ++r)
            mreg[rt][r] = mt[((size_t)(rw + rt * 16 + quad * 4 + r) * 16 + ln) * 4 + w];

    const float NEGINF = -__builtin_inff();
    float m4[2][4];
#pragma unroll
    for (int rt = 0; rt < 2; ++rt)
#pragma unroll
        for (int r = 0; r < 4; ++r) m4[rt][r] = NEGINF;
    int ct0 = w * 64;   // this wave's 64 column tiles (1024 columns)

    // PASS A: masked row-max; 32 iterations x 2 col-tiles shared by both row-tiles
    for (int fi = 0; fi < 32; ++fi) {
        BFrag bt[2];
#pragma unroll
        for (int tt = 0; tt < 2; ++tt) bt[tt] = load_bfrag(hfh, hfl, ct0 + fi * 2 + tt, lane);
#pragma unroll
        for (int tt = 0; tt < 2; ++tt) {
            int bi = fi * 2 + tt;
#pragma unroll
            for (int rt = 0; rt < 2; ++rt) {
                f32x4 s = sim_mfma(bt[tt], ah0[rt], ah1[rt], al0[rt], al1[rt]);
#pragma unroll
                for (int r = 0; r < 4; ++r) {
                    unsigned int bit = (unsigned int)(mreg[rt][r] >> bi) & 1u;
                    float v = bit ? s[r] : NEGINF;
                    m4[rt][r] = fmaxf(m4[rt][r], v);
                }
            }
        }
    }
#pragma unroll
    for (int rt = 0; rt < 2; ++rt)
#pragma unroll
        for (int r = 0; r < 4; ++r) {
            float v = m4[rt][r];
            v = fmaxf(v, __shfl_xor(v, 1, 64));
            v = fmaxf(v, __shfl_xor(v, 2, 64));
            v = fmaxf(v, __shfl_xor(v, 4, 64));
            v = fmaxf(v, __shfl_xor(v, 8, 64));
            if (ln == 0) maxb[w][rt * 16 + quad * 4 + r] = v;
        }
    __syncthreads();
#pragma unroll
    for (int rt = 0; rt < 2; ++rt)
#pragma unroll
        for (int r = 0; r < 4; ++r) {
            int row = rt * 16 + quad * 4 + r;
            m4[rt][r] = fmaxf(fmaxf(maxb[0][row], maxb[1][row]),
                              fmaxf(maxb[2][row], maxb[3][row]));
        }

    // PASS B: recompute (bit-identical), keep rule, exp, partial l and partial PV
    const bf16* tfh = htf_hi + (size_t)head * HSTRIDE;
    const bf16* tfl = htf_lo + (size_t)head * HSTRIDE;
    float l4[2][4];
    f32x4 pv[2][4];
#pragma unroll
    for (int rt = 0; rt < 2; ++rt)
#pragma unroll
        for (int r = 0; r < 4; ++r) {
            l4[rt][r] = 0.f;
            pv[rt][r] = (f32x4){0.f, 0.f, 0.f, 0.f};
        }
    bf16* P0 = &Plds[w][0][0];
    bf16* P1 = &Plds[w][1][0];
    for (int fi = 0; fi < 32; ++fi) {
        BFrag bt[2];
#pragma unroll
        for (int tt = 0; tt < 2; ++tt) bt[tt] = load_bfrag(hfh, hfl, ct0 + fi * 2 + tt, lane);
#pragma unroll
        for (int tt = 0; tt < 2; ++tt) {
            int bi = fi * 2 + tt;
#pragma unroll
            for (int rt = 0; rt < 2; ++rt) {
                f32x4 s = sim_mfma(bt[tt], ah0[rt], ah1[rt], al0[rt], al1[rt]);
                bf16* P = rt ? P1 : P0;
#pragma unroll
                for (int r = 0; r < 4; ++r) {
                    unsigned int bit = (unsigned int)(mreg[rt][r] >> bi) & 1u;
                    bool keep = bit && (s[r] >= 0.5f * m4[rt][r]);
                    float arg = keep ? 5.0f * (s[r] - m4[rt][r]) : NEGINF;
                    float p = __expf(arg);
                    bf16 pb = __float2bfloat16(p);
                    l4[rt][r] += __bfloat162float(pb);   // denominator from the ROUNDED p
                    P[(quad * 4 + r) * 36 + tt * 16 + ln] = pb;
                }
            }
        }
        __builtin_amdgcn_wave_barrier();
        bf16x8 pa0 = *(const bf16x8*)(P0 + ln * 36 + quad * 8);
        bf16x8 pa1 = *(const bf16x8*)(P1 + ln * 36 + quad * 8);
        int c0 = w * 1024 + fi * 32;
        int g = c0 >> 6, half = (c0 >> 5) & 1;
#pragma unroll
        for (int nt = 0; nt < 4; ++nt) {
            size_t base = (size_t)(g * 8 + nt * 2 + half) * 512 + lane * 8;
            bf16x8 bh = *(const bf16x8*)(tfh + base);
            bf16x8 bl = *(const bf16x8*)(tfl + base);
            pv[0][nt] = __builtin_amdgcn_mfma_f32_16x16x32_bf16(pa0, bh, pv[0][nt], 0, 0, 0);
            pv[0][nt] = __builtin_amdgcn_mfma_f32_16x16x32_bf16(pa0, bl, pv[0][nt], 0, 0, 0);
            pv[1][nt] = __builtin_amdgcn_mfma_f32_16x16x32_bf16(pa1, bh, pv[1][nt], 0, 0, 0);
            pv[1][nt] = __builtin_amdgcn_mfma_f32_16x16x32_bf16(pa1, bl, pv[1][nt], 0, 0, 0);
        }
        __builtin_amdgcn_wave_barrier();
    }

    // cross-wave reduce + epilogue, one row-tile at a time
    for (int rt = 0; rt < 2; ++rt) {
#pragma unroll
        for (int r = 0; r < 4; ++r) {
            float v = l4[rt][r];
            v += __shfl_xor(v, 1, 64);
            v += __shfl_xor(v, 2, 64);
            v += __shfl_xor(v, 4, 64);
            v += __shfl_xor(v, 8, 64);
            if (ln == 0) lbuf[w][quad * 4 + r] = v;
        }
#pragma unroll
        for (int nt = 0; nt < 4; ++nt)
#pragma unroll
            for (int r = 0; r < 4; ++r)
                pvbuf[w][quad * 4 + r][nt * 16 + ln] = pv[rt][nt][r];
        __syncthreads();
        {
            int row = t >> 4;
            int c4 = (t & 15) * 4;
            float lsum = lbuf[0][row] + lbuf[1][row] + lbuf[2][row] + lbuf[3][row];
            float inv = (lsum > 0.f) ? 1.0f / lsum : 0.f;
            float4 o;
            float* op = &o.x;
#pragma unroll
            for (int i = 0; i < 4; ++i) {
                int col = c4 + i;
                float v = pvbuf[0][row][col] + pvbuf[1][row][col]
                        + pvbuf[2][row][col] + pvbuf[3][row][col];
                v = (lsum > 0.f) ? v * inv : colmean[head * 64 + col];
                op[i] = (v > 0.f) ? v : (__expf(v) - 1.0f);
            }
            *(float4*)(hout + ((size_t)head * N + rw + rt * 16 + row) * 64 + c4) = o;
        }
        __syncthreads();
    }
}

__global__ void k_combine(const float* __restrict__ hout, float* __restrict__ feat,
                          float* __restrict__ outp, int last) {
    int i = blockIdx.x * 256 + threadIdx.x;
    float v = 0.25f * (hout[i] + hout[i + N * 64] + hout[i + 2 * N * 64] + hout[i + 3 * N * 64]);
    if (last) outp[i] = v;
    else feat[i] = v;
}

extern "C" void kernel_launch(void* const* d_in, const int* in_sizes, int n_in,
                              void* d_out, int out_size, void* d_ws, size_t ws_size,
                              hipStream_t stream) {
    const float* features_in = (const float*)d_in[0];
    const int* adj = (const int*)d_in[1];
    const float* Ws = (const float*)d_in[2];
    char* ws = (char*)d_ws;
    u64* mt = (u64*)(ws + OFF_MASK);
    float* feat = (float*)(ws + OFF_FEAT);
    bf16* hnf_hi = (bf16*)(ws + OFF_HNHI);
    bf16* hnf_lo = (bf16*)(ws + OFF_HNLO);
    bf16* htf_hi = (bf16*)(ws + OFF_HTHI);
    bf16* htf_lo = (bf16*)(ws + OFF_HTLO);
    float* hout = (float*)(ws + OFF_HOUT);
    float* cm = (float*)(ws + OFF_CM);

    k_packadj<<<dim3(NSTEP * N / 16), dim3(256), 0, stream>>>(adj, mt);
    for (int s = 0; s < NSTEP; ++s) {
        hipMemsetAsync(cm, 0, NH * D * sizeof(float), stream);
        const float* X = (s == 0) ? features_in : feat;
        k_phase0<<<dim3(256), dim3(256), 0, stream>>>(X, Ws + (size_t)s * NH * D * D,
                                                      hnf_hi, hnf_lo, htf_hi, htf_lo, cm);
        k_attn<<<dim3(N / 32 * NH), dim3(256), 0, stream>>>(hnf_hi, hnf_lo, htf_hi, htf_lo,
                                                            mt + (size_t)s * N * 64, cm, hout);
        k_combine<<<dim3(N * D / 256), dim3(256), 0, stream>>>(hout, feat, (float*)d_out, s == NSTEP - 1);
    }
}

// Round 13
// 781.948 us; speedup vs baseline: 1.1408x; 1.0127x over previous
//
#include <hip/hip_runtime.h>
#include <hip/hip_bf16.h>

#define N 4096
#define D 64
#define NH 4
#define NSTEP 4
#define HSTRIDE 262144   // elements per head in fragment-major arrays (4096*64)

typedef short bf16x8 __attribute__((ext_vector_type(8)));
typedef float f32x4 __attribute__((ext_vector_type(4)));
typedef __hip_bfloat16 bf16;
typedef unsigned long long u64;

// ws layout (bytes)
static const size_t OFF_MASK = 0;                              // NSTEP*N*64 u64 = 8 MB
static const size_t OFF_FEAT = (size_t)8 << 20;                // N*D f32 = 1 MB
static const size_t OFF_HNHI = (size_t)9 << 20;                // NH*HSTRIDE bf16 = 2 MB
static const size_t OFF_HNLO = (size_t)11 << 20;               // 2 MB
static const size_t OFF_HTHI = (size_t)13 << 20;               // 2 MB
static const size_t OFF_HTLO = (size_t)15 << 20;               // 2 MB
static const size_t OFF_HOUT = (size_t)17 << 20;               // NH*N*D f32 = 4 MB
static const size_t OFF_CM   = (size_t)21 << 20;               // NH*D f32

// Coalesced mask pack (R8 version). mt[row][ln][w] (u64),
// bit i = adj[row][w*1024 + i*16 + ln].
__global__ void k_packadj(const int* __restrict__ adj, u64* __restrict__ mt) {
    int t = threadIdx.x;
    int lane = t & 63;
    int row = blockIdx.x * 16 + (t >> 6) * 4 + (lane >> 4);   // 16 rows per block
    int sub = lane & 15;
    int w = sub & 3;
    int c4 = sub >> 2;
    const int* rowp = adj + (size_t)row * N + w * 1024 + c4 * 4;
    u64 m0 = 0, m1 = 0, m2 = 0, m3 = 0;
    for (int i = 0; i < 64; ++i) {
        int4 v = *(const int4*)(rowp + i * 16);
        u64 b = 1ull << i;
        if (v.x > 0) m0 |= b;
        if (v.y > 0) m1 |= b;
        if (v.z > 0) m2 |= b;
        if (v.w > 0) m3 |= b;
    }
    u64* out = mt + (size_t)row * 64;
    out[(c4 * 4 + 0) * 4 + w] = m0;
    out[(c4 * 4 + 1) * 4 + w] = m1;
    out[(c4 * 4 + 2) * 4 + w] = m2;
    out[(c4 * 4 + 3) * 4 + w] = m3;
}

// h = X @ W[head] in fp32; fragment-major hi/lo outputs written coalesced via LDS.
// 1D grid with the SAME head->XCD pinning as k_attn.
__global__ void k_phase0(const float* __restrict__ X, const float* __restrict__ W,
                         bf16* __restrict__ hnf_hi, bf16* __restrict__ hnf_lo,
                         bf16* __restrict__ htf_hi, bf16* __restrict__ htf_lo,
                         float* __restrict__ colmean) {
    __shared__ float Xs[64][65];
    __shared__ float Wsh[64][64];
    __shared__ float hbuf[64][68];
    __shared__ float rnbuf[64];
    __shared__ float colsum[64];
    int bid = blockIdx.x;
    int head = (bid & 7) >> 1;
    int rb = ((bid >> 3) << 1) | (bid & 1);
    int r0 = rb * 64;
    int t = threadIdx.x;
    for (int i = 0; i < 16; ++i) {
        int idx = t + 256 * i;
        int r = idx >> 6, c = idx & 63;
        Xs[r][c] = X[(size_t)(r0 + r) * 64 + c];
        Wsh[r][c] = W[(size_t)head * 4096 + idx];
    }
    if (t < 64) colsum[t] = 0.f;
    __syncthreads();
    int lane = t & 63, w = t >> 6;
    int lr = w * 16 + (lane >> 2);
    int e0 = (lane & 3) * 16;
    float acc[16];
#pragma unroll
    for (int j = 0; j < 16; ++j) acc[j] = 0.f;
    for (int d = 0; d < 64; ++d) {
        float xv = Xs[lr][d];
#pragma unroll
        for (int j = 0; j < 16; ++j) acc[j] = fmaf(xv, Wsh[d][e0 + j], acc[j]);
    }
    float ss = 0.f;
#pragma unroll
    for (int j = 0; j < 16; ++j) ss = fmaf(acc[j], acc[j], ss);
    ss += __shfl_xor(ss, 1, 64);
    ss += __shfl_xor(ss, 2, 64);
    float rn = 1.0f / (sqrtf(ss) + 1e-12f);
#pragma unroll
    for (int j = 0; j < 16; ++j) hbuf[lr][e0 + j] = acc[j];
    if ((lane & 3) == 0) rnbuf[lr] = rn;
#pragma unroll
    for (int j = 0; j < 16; ++j) {
        float v = acc[j];
        v += __shfl_xor(v, 4, 64);
        v += __shfl_xor(v, 8, 64);
        v += __shfl_xor(v, 16, 64);
        v += __shfl_xor(v, 32, 64);
        if ((lane >> 2) == 0) atomicAdd(&colsum[e0 + j], v);
    }
    __syncthreads();
    if (t < 64) atomicAdd(&colmean[head * 64 + t], colsum[t] * (1.0f / N));

    size_t hb = (size_t)head * HSTRIDE;
    size_t hnbase = hb + (size_t)r0 * 64;
    size_t htbase = hb + (size_t)rb * 4096;
#pragma unroll
    for (int u = 0; u < 2; ++u) {
        int idx16 = t * 2 + u;
        {
            int lnn = idx16 & 15, q = (idx16 >> 4) & 3, half = (idx16 >> 6) & 1, ctl = idx16 >> 7;
            int row = ctl * 16 + lnn, d0 = half * 32 + q * 8;
            float rr = rnbuf[row];
            bf16x8 hi8, lo8;
#pragma unroll
            for (int j = 0; j < 8; ++j) {
                float hnv = hbuf[row][d0 + j] * rr;
                bf16 nhi = __float2bfloat16(hnv);
                bf16 nlo = __float2bfloat16(hnv - __bfloat162float(nhi));
                hi8[j] = *(short*)&nhi;
                lo8[j] = *(short*)&nlo;
            }
            *(bf16x8*)(hnf_hi + hnbase + (size_t)idx16 * 8) = hi8;
            *(bf16x8*)(hnf_lo + hnbase + (size_t)idx16 * 8) = lo8;
        }
        {
            int dln = idx16 & 15, qq = (idx16 >> 4) & 3, half = (idx16 >> 6) & 1, nt = idx16 >> 7;
            int d = nt * 16 + dln, cbase = half * 32 + qq * 8;
            bf16x8 hi8, lo8;
#pragma unroll
            for (int j = 0; j < 8; ++j) {
                float hv = hbuf[cbase + j][d];
                bf16 hhi = __float2bfloat16(hv);
                bf16 hlo = __float2bfloat16(hv - __bfloat162float(hhi));
                hi8[j] = *(short*)&hhi;
                lo8[j] = *(short*)&hlo;
            }
            *(bf16x8*)(htf_hi + htbase + (size_t)idx16 * 8) = hi8;
            *(bf16x8*)(htf_lo + htbase + (size_t)idx16 * 8) = lo8;
        }
    }
}

struct BFrag { bf16x8 h0, h1, l0, l1; };

__device__ __forceinline__ BFrag load_bfrag(const bf16* __restrict__ hfh,
                                            const bf16* __restrict__ hfl,
                                            int ct, int lane) {
    BFrag f;
    size_t base = (size_t)ct * 1024 + lane * 8;
    f.h0 = *(const bf16x8*)(hfh + base);
    f.h1 = *(const bf16x8*)(hfh + base + 512);
    f.l0 = *(const bf16x8*)(hfl + base);
    f.l1 = *(const bf16x8*)(hfl + base + 512);
    return f;
}

// split-bf16 sim: identical sequence in both passes -> bit-identical keep rule.
__device__ __forceinline__ f32x4 sim_mfma(const BFrag& b,
                                          bf16x8 a0h, bf16x8 a1h, bf16x8 a0l, bf16x8 a1l) {
    f32x4 s = {0.f, 0.f, 0.f, 0.f};
    s = __builtin_amdgcn_mfma_f32_16x16x32_bf16(a0h, b.h0, s, 0, 0, 0);
    s = __builtin_amdgcn_mfma_f32_16x16x32_bf16(a1h, b.h1, s, 0, 0, 0);
    s = __builtin_amdgcn_mfma_f32_16x16x32_bf16(a0l, b.h0, s, 0, 0, 0);
    s = __builtin_amdgcn_mfma_f32_16x16x32_bf16(a1l, b.h1, s, 0, 0, 0);
    s = __builtin_amdgcn_mfma_f32_16x16x32_bf16(a0h, b.l0, s, 0, 0, 0);
    s = __builtin_amdgcn_mfma_f32_16x16x32_bf16(a1h, b.l1, s, 0, 0, 0);
    return s;
}

// fused two-pass masked attention (R8 structure). Block = 32 rows (two 16-row tiles
// sharing every B-fragment load), 256 threads: 4 waves x 1024 columns.
// R13: NO wave_barriers in pass B; P tile double-buffered by fi parity so the
// compiler can software-pipeline loads across the LDS round-trip.
__launch_bounds__(256, 2)
__global__ void k_attn(const bf16* __restrict__ hnf_hi, const bf16* __restrict__ hnf_lo,
                       const bf16* __restrict__ htf_hi, const bf16* __restrict__ htf_lo,
                       const u64* __restrict__ mt,
                       const float* __restrict__ colmean,
                       float* __restrict__ hout) {
    __shared__ bf16 Plds[2][4][2][16 * 36];   // parity x wave x rt x (16 rows x 32 cols)
    __shared__ float maxb[4][32];
    __shared__ float lbuf[4][16];
    __shared__ float pvbuf[4][16][66];
    int bid = blockIdx.x;
    int head = (bid & 7) >> 1;
    int rw = (((bid >> 3) << 1) | (bid & 1)) * 32;
    int t = threadIdx.x;
    int w = t >> 6, lane = t & 63;
    int ln = lane & 15, quad = lane >> 4;
    const bf16* hfh = hnf_hi + (size_t)head * HSTRIDE;
    const bf16* hfl = hnf_lo + (size_t)head * HSTRIDE;
    bf16x8 ah0[2], ah1[2], al0[2], al1[2];
#pragma unroll
    for (int rt = 0; rt < 2; ++rt) {
        size_t base = (size_t)((rw >> 4) + rt) * 1024 + lane * 8;
        ah0[rt] = *(const bf16x8*)(hfh + base);
        ah1[rt] = *(const bf16x8*)(hfh + base + 512);
        al0[rt] = *(const bf16x8*)(hfl + base);
        al1[rt] = *(const bf16x8*)(hfl + base + 512);
    }
    u64 mreg[2][4];
#pragma unroll
    for (int rt = 0; rt < 2; ++rt)
#pragma unroll
        for (int r = 0; r < 4; ++r)
            mreg[rt][r] = mt[((size_t)(rw + rt * 16 + quad * 4 + r) * 16 + ln) * 4 + w];

    const float NEGINF = -__builtin_inff();
    float m4[2][4];
#pragma unroll
    for (int rt = 0; rt < 2; ++rt)
#pragma unroll
        for (int r = 0; r < 4; ++r) m4[rt][r] = NEGINF;
    int ct0 = w * 64;   // this wave's 64 column tiles (1024 columns)

    // PASS A: masked row-max; 32 iterations x 2 col-tiles shared by both row-tiles
    for (int fi = 0; fi < 32; ++fi) {
        BFrag bt[2];
#pragma unroll
        for (int tt = 0; tt < 2; ++tt) bt[tt] = load_bfrag(hfh, hfl, ct0 + fi * 2 + tt, lane);
#pragma unroll
        for (int tt = 0; tt < 2; ++tt) {
            int bi = fi * 2 + tt;
#pragma unroll
            for (int rt = 0; rt < 2; ++rt) {
                f32x4 s = sim_mfma(bt[tt], ah0[rt], ah1[rt], al0[rt], al1[rt]);
#pragma unroll
                for (int r = 0; r < 4; ++r) {
                    unsigned int bit = (unsigned int)(mreg[rt][r] >> bi) & 1u;
                    float v = bit ? s[r] : NEGINF;
                    m4[rt][r] = fmaxf(m4[rt][r], v);
                }
            }
        }
    }
#pragma unroll
    for (int rt = 0; rt < 2; ++rt)
#pragma unroll
        for (int r = 0; r < 4; ++r) {
            float v = m4[rt][r];
            v = fmaxf(v, __shfl_xor(v, 1, 64));
            v = fmaxf(v, __shfl_xor(v, 2, 64));
            v = fmaxf(v, __shfl_xor(v, 4, 64));
            v = fmaxf(v, __shfl_xor(v, 8, 64));
            if (ln == 0) maxb[w][rt * 16 + quad * 4 + r] = v;
        }
    __syncthreads();
#pragma unroll
    for (int rt = 0; rt < 2; ++rt)
#pragma unroll
        for (int r = 0; r < 4; ++r) {
            int row = rt * 16 + quad * 4 + r;
            m4[rt][r] = fmaxf(fmaxf(maxb[0][row], maxb[1][row]),
                              fmaxf(maxb[2][row], maxb[3][row]));
        }

    // PASS B: recompute (bit-identical), keep rule, exp, partial l and partial PV.
    // No wave_barriers; P double-buffered by parity -> compiler free to pipeline.
    const bf16* tfh = htf_hi + (size_t)head * HSTRIDE;
    const bf16* tfl = htf_lo + (size_t)head * HSTRIDE;
    float l4[2][4];
    f32x4 pv[2][4];
#pragma unroll
    for (int rt = 0; rt < 2; ++rt)
#pragma unroll
        for (int r = 0; r < 4; ++r) {
            l4[rt][r] = 0.f;
            pv[rt][r] = (f32x4){0.f, 0.f, 0.f, 0.f};
        }
    for (int fi = 0; fi < 32; ++fi) {
        int par = fi & 1;
        bf16* P0 = &Plds[par][w][0][0];
        bf16* P1 = &Plds[par][w][1][0];
        BFrag bt[2];
#pragma unroll
        for (int tt = 0; tt < 2; ++tt) bt[tt] = load_bfrag(hfh, hfl, ct0 + fi * 2 + tt, lane);
#pragma unroll
        for (int tt = 0; tt < 2; ++tt) {
            int bi = fi * 2 + tt;
#pragma unroll
            for (int rt = 0; rt < 2; ++rt) {
                f32x4 s = sim_mfma(bt[tt], ah0[rt], ah1[rt], al0[rt], al1[rt]);
                bf16* P = rt ? P1 : P0;
#pragma unroll
                for (int r = 0; r < 4; ++r) {
                    unsigned int bit = (unsigned int)(mreg[rt][r] >> bi) & 1u;
                    bool keep = bit && (s[r] >= 0.5f * m4[rt][r]);
                    float arg = keep ? 5.0f * (s[r] - m4[rt][r]) : NEGINF;
                    float p = __expf(arg);
                    bf16 pb = __float2bfloat16(p);
                    l4[rt][r] += __bfloat162float(pb);   // denominator from the ROUNDED p
                    P[(quad * 4 + r) * 36 + tt * 16 + ln] = pb;
                }
            }
        }
        bf16x8 pa0 = *(const bf16x8*)(P0 + ln * 36 + quad * 8);
        bf16x8 pa1 = *(const bf16x8*)(P1 + ln * 36 + quad * 8);
        int c0 = w * 1024 + fi * 32;
        int g = c0 >> 6, half = (c0 >> 5) & 1;
#pragma unroll
        for (int nt = 0; nt < 4; ++nt) {
            size_t base = (size_t)(g * 8 + nt * 2 + half) * 512 + lane * 8;
            bf16x8 bh = *(const bf16x8*)(tfh + base);
            bf16x8 bl = *(const bf16x8*)(tfl + base);
            pv[0][nt] = __builtin_amdgcn_mfma_f32_16x16x32_bf16(pa0, bh, pv[0][nt], 0, 0, 0);
            pv[0][nt] = __builtin_amdgcn_mfma_f32_16x16x32_bf16(pa0, bl, pv[0][nt], 0, 0, 0);
            pv[1][nt] = __builtin_amdgcn_mfma_f32_16x16x32_bf16(pa1, bh, pv[1][nt], 0, 0, 0);
            pv[1][nt] = __builtin_amdgcn_mfma_f32_16x16x32_bf16(pa1, bl, pv[1][nt], 0, 0, 0);
        }
    }

    // cross-wave reduce + epilogue, one row-tile at a time
    for (int rt = 0; rt < 2; ++rt) {
#pragma unroll
        for (int r = 0; r < 4; ++r) {
            float v = l4[rt][r];
            v += __shfl_xor(v, 1, 64);
            v += __shfl_xor(v, 2, 64);
            v += __shfl_xor(v, 4, 64);
            v += __shfl_xor(v, 8, 64);
            if (ln == 0) lbuf[w][quad * 4 + r] = v;
        }
#pragma unroll
        for (int nt = 0; nt < 4; ++nt)
#pragma unroll
            for (int r = 0; r < 4; ++r)
                pvbuf[w][quad * 4 + r][nt * 16 + ln] = pv[rt][nt][r];
        __syncthreads();
        {
            int row = t >> 4;
            int c4 = (t & 15) * 4;
            float lsum = lbuf[0][row] + lbuf[1][row] + lbuf[2][row] + lbuf[3][row];
            float inv = (lsum > 0.f) ? 1.0f / lsum : 0.f;
            float4 o;
            float* op = &o.x;
#pragma unroll
            for (int i = 0; i < 4; ++i) {
                int col = c4 + i;
                float v = pvbuf[0][row][col] + pvbuf[1][row][col]
                        + pvbuf[2][row][col] + pvbuf[3][row][col];
                v = (lsum > 0.f) ? v * inv : colmean[head * 64 + col];
                op[i] = (v > 0.f) ? v : (__expf(v) - 1.0f);
            }
            *(float4*)(hout + ((size_t)head * N + rw + rt * 16 + row) * 64 + c4) = o;
        }
        __syncthreads();
    }
}

__global__ void k_combine(const float* __restrict__ hout, float* __restrict__ feat,
                          float* __restrict__ outp, int last) {
    int i = blockIdx.x * 256 + threadIdx.x;
    float v = 0.25f * (hout[i] + hout[i + N * 64] + hout[i + 2 * N * 64] + hout[i + 3 * N * 64]);
    if (last) outp[i] = v;
    else feat[i] = v;
}

extern "C" void kernel_launch(void* const* d_in, const int* in_sizes, int n_in,
                              void* d_out, int out_size, void* d_ws, size_t ws_size,
                              hipStream_t stream) {
    const float* features_in = (const float*)d_in[0];
    const int* adj = (const int*)d_in[1];
    const float* Ws = (const float*)d_in[2];
    char* ws = (char*)d_ws;
    u64* mt = (u64*)(ws + OFF_MASK);
    float* feat = (float*)(ws + OFF_FEAT);
    bf16* hnf_hi = (bf16*)(ws + OFF_HNHI);
    bf16* hnf_lo = (bf16*)(ws + OFF_HNLO);
    bf16* htf_hi = (bf16*)(ws + OFF_HTHI);
    bf16* htf_lo = (bf16*)(ws + OFF_HTLO);
    float* hout = (float*)(ws + OFF_HOUT);
    float* cm = (float*)(ws + OFF_CM);

    k_packadj<<<dim3(NSTEP * N / 16), dim3(256), 0, stream>>>(adj, mt);
    for (int s = 0; s < NSTEP; ++s) {
        hipMemsetAsync(cm, 0, NH * D * sizeof(float), stream);
        const float* X = (s == 0) ? features_in : feat;
        k_phase0<<<dim3(256), dim3(256), 0, stream>>>(X, Ws + (size_t)s * NH * D * D,
                                                      hnf_hi, hnf_lo, htf_hi, htf_lo, cm);
        k_attn<<<dim3(N / 32 * NH), dim3(256), 0, stream>>>(hnf_hi, hnf_lo, htf_hi, htf_lo,
                                                            mt + (size_t)s * N * 64, cm, hout);
        k_combine<<<dim3(N * D / 256), dim3(256), 0, stream>>>(hout, feat, (float*)d_out, s == NSTEP - 1);
    }
}